// Round 6
// baseline (101.587 us; speedup 1.0000x reference)
//
#include <hip/hip_runtime.h>

// ---------------------------------------------------------------------------
// Stacked 3-layer LSTM step + projection, B=256, I=512, H=1024, V=512 (fp32 io)
// Round 6: A-direct GEMM. A (bf16, L2-resident) loaded per-wave straight from
// global as MFMA fragments; only W (fp32->bf16, needs transpose) goes through
// LDS (2 x 4 KB double buffer). BM=256 (W read once), BN=32, 8 waves,
// raw s_barrier + lgkmcnt(0) so depth-3 W / depth-2 A prefetch survives
// barriers. 2 blocks/CU. Launch graph: mega {x@W0,h0@U0,h1@U1,h2@U2} then
// serial gates0 -> h0n@W1 -> gates1 -> h1n@W2 -> gates2 -> h2n@Wp -> proj.
// ---------------------------------------------------------------------------

typedef __attribute__((ext_vector_type(8))) short short8_t;            // 8 bf16 (MFMA frag)
typedef __attribute__((ext_vector_type(4))) unsigned short ushort4_t;  // 8B st
typedef __attribute__((ext_vector_type(4))) float f32x4;               // MFMA acc / 16B ld

__device__ __forceinline__ unsigned short f2bf(float f) {
    union { float f; unsigned u; } v; v.f = f;
    unsigned r = v.u + 0x7FFFu + ((v.u >> 16) & 1u);   // RTNE (finite inputs)
    return (unsigned short)(r >> 16);
}

#define KT 64
#define BN 32

struct GemmPiece {
    const unsigned short* A;   // [256][K] bf16 bits
    const float*          W;   // [K][N] fp32
    float*                Z;   // partials: [1<<lgs][256][N]
    int K;
    int lgs;                   // K-split log2
    int bstart;                // first block id of this piece
};
struct GemmDesc { GemmPiece p[4]; int np; int N; };

// ---------------------------------------------------------------------------
// Z[kb][256][N] = A[256][K-slice kb] @ W[K-slice kb][N]   (per piece)
// Block: 512 thr (8 waves), BM=256, BN=32. Wave w: rows w*32..+32, 2x2 MFMA
// tiles. A frags direct from global (no LDS); W via 2x4KB LDS dbuf.
// ---------------------------------------------------------------------------
__global__ __launch_bounds__(512, 4)
void gemm_aw(GemmDesc d)
{
    __shared__ unsigned short Wl0[BN * KT];    // 4 KB, [n][k] transposed, swizzled
    __shared__ unsigned short Wl1[BN * KT];    // 4 KB

    const int bid = blockIdx.x;
    int pi = 0;
#pragma unroll
    for (int i = 1; i < 4; ++i)
        if (i < d.np && bid >= d.p[i].bstart) pi = i;
    const unsigned short* __restrict__ A = d.p[pi].A;
    const float* __restrict__ W = d.p[pi].W;
    const int K   = d.p[pi].K;
    const int lgs = d.p[pi].lgs;
    const int N   = d.N;
    const int lb  = bid - d.p[pi].bstart;
    const int nsplit = 1 << lgs;
    const int kb  = lb & (nsplit - 1);
    const int ns  = lb >> lgs;

    const int tid  = threadIdx.x;
    const int lane = tid & 63;
    const int w    = tid >> 6;
    const int lg   = lane >> 4;
    const int lr   = lane & 15;
    const int n0   = ns * BN;
    const int m0   = w * 32;
    const int klen = K >> lgs;
    const int kbeg = kb * klen;
    const int nt   = klen >> 6;            // 2,4,8,16

    const int wkr = tid >> 3;              // W k-row within tile 0..63
    const int wcq = tid & 7;               // W float4-col 0..7

    // prefetch register sets (statically named - rule #20)
    short8_t a0[4], a1[4], a2[4];          // A frags: (ks0,r0),(ks0,r1),(ks1,r0),(ks1,r1)
    f32x4    w0v, w1v, w2v;                // W row-chunks

    f32x4 acc00 = {0,0,0,0}, acc01 = {0,0,0,0}, acc10 = {0,0,0,0}, acc11 = {0,0,0,0};

    auto issueW = [&](int t, f32x4& wv) {
        int k0 = kbeg + t * KT;
        wv = *(const f32x4*)(W + (size_t)(k0 + wkr) * N + n0 + wcq * 4);
    };

    auto issueA = [&](int t, short8_t (&a)[4]) {
        int k0 = kbeg + t * KT;
        const unsigned short* base = A + (size_t)(m0 + lr) * K + k0 + lg * 8;
        a[0] = *(const short8_t*)(base);
        a[1] = *(const short8_t*)(base + (size_t)16 * K);
        a[2] = *(const short8_t*)(base + 32);
        a[3] = *(const short8_t*)(base + (size_t)16 * K + 32);
    };

    auto stageW = [&](const f32x4& wv, unsigned short* wl) {
        int kch = wkr >> 3, kwi = wkr & 7;
#pragma unroll
        for (int j = 0; j < 4; ++j) {
            int n = wcq * 4 + j;           // transposed: Wl[n][k], 16B-chunk XOR swizzle
            wl[n * KT + ((kch ^ (n & 7)) << 3) + kwi] = f2bf(wv[j]);
        }
    };

    auto compute = [&](const unsigned short* wl, short8_t (&a)[4]) {
#pragma unroll
        for (int ks = 0; ks < 2; ++ks) {
            int ch = ks * 4 + lg;
            int nb0 = lr, nb1 = 16 + lr;
            short8_t b0f = *(const short8_t*)(wl + nb0 * KT + ((ch ^ (nb0 & 7)) << 3));
            short8_t b1f = *(const short8_t*)(wl + nb1 * KT + ((ch ^ (nb1 & 7)) << 3));
            acc00 = __builtin_amdgcn_mfma_f32_16x16x32_bf16(a[ks * 2],     b0f, acc00, 0, 0, 0);
            acc01 = __builtin_amdgcn_mfma_f32_16x16x32_bf16(a[ks * 2],     b1f, acc01, 0, 0, 0);
            acc10 = __builtin_amdgcn_mfma_f32_16x16x32_bf16(a[ks * 2 + 1], b0f, acc10, 0, 0, 0);
            acc11 = __builtin_amdgcn_mfma_f32_16x16x32_bf16(a[ks * 2 + 1], b1f, acc11, 0, 0, 0);
        }
    };

#define BAR() do { asm volatile("s_waitcnt lgkmcnt(0)" ::: "memory"); \
                   __builtin_amdgcn_s_barrier(); } while (0)

    // prologue: W depth-3, A depth-2, tile 0 staged
    issueW(0, w0v);
    if (1 < nt) issueW(1, w1v);
    issueA(0, a0);
    stageW(w0v, Wl0);
    if (2 < nt) issueW(2, w2v);
    if (1 < nt) issueA(1, a1);
    BAR();                                 // Wl0 (tile 0) published

    // phase p: stage w[(p+1)%3]->Wl[(p+1)&1]; issueW(p+3); issueA(p+2);
    //          compute(Wl[p&1], a[p%3]); barrier.
#define PHASE(p, WST, WLST, WIS, AIS, WLC, ACM) \
    if ((p) < nt) { \
        if ((p) + 1 < nt) stageW(WST, WLST); \
        if ((p) + 3 < nt) issueW((p) + 3, WIS); \
        if ((p) + 2 < nt) issueA((p) + 2, AIS); \
        compute(WLC, ACM); \
        BAR(); \
    }

    for (int t = 0; t < nt; t += 6) {
        PHASE(t + 0, w1v, Wl1, w0v, a2, Wl0, a0)
        PHASE(t + 1, w2v, Wl0, w1v, a0, Wl1, a1)
        PHASE(t + 2, w0v, Wl1, w2v, a1, Wl0, a2)
        PHASE(t + 3, w1v, Wl0, w0v, a2, Wl1, a0)
        PHASE(t + 4, w2v, Wl1, w1v, a0, Wl0, a1)
        PHASE(t + 5, w0v, Wl0, w2v, a1, Wl1, a2)
    }
#undef PHASE
#undef BAR

    // epilogue: D mapping col=lane&15, row=4*(lane>>4)+reg  [m89/m91]
    float* zrow = d.p[pi].Z + (size_t)kb * 256 * N;
#pragma unroll
    for (int r = 0; r < 4; ++r) {
        int ma = m0 + lg * 4 + r;
        int mb = ma + 16;
        zrow[(size_t)ma * N + n0 + lr]      = acc00[r];
        zrow[(size_t)ma * N + n0 + 16 + lr] = acc01[r];
        zrow[(size_t)mb * N + n0 + lr]      = acc10[r];
        zrow[(size_t)mb * N + n0 + 16 + lr] = acc11[r];
    }
}

// ---------------------------------------------------------------------------
// Gates: z = sum(pz1[0..n1)) + sum(pz2[0..n2)) + bias -> h,c fp32 + h bf16
// Partial stride = 1048576 floats (one [256][4096] slot).
// ---------------------------------------------------------------------------
__global__ __launch_bounds__(256)
void lstm_gates(const float* __restrict__ pz1, int n1,
                const float* __restrict__ pz2, int n2,
                const float* __restrict__ bias, const float* __restrict__ c_old,
                float* __restrict__ h_out, float* __restrict__ c_out,
                unsigned short* __restrict__ h_bf)
{
    int t = blockIdx.x * 256 + threadIdx.x;   // 65536 threads, 4 elems each
    int b = t >> 8;
    int n = (t & 255) << 2;
    f32x4 iv = *(const f32x4*)(bias + n);
    f32x4 fv = *(const f32x4*)(bias + 1024 + n);
    f32x4 gv = *(const f32x4*)(bias + 2048 + n);
    f32x4 ov = *(const f32x4*)(bias + 3072 + n);
    for (int i = 0; i < n1; ++i) {
        const float* z = pz1 + (size_t)i * 1048576 + (size_t)b * 4096;
        iv += *(const f32x4*)(z + n);
        fv += *(const f32x4*)(z + 1024 + n);
        gv += *(const f32x4*)(z + 2048 + n);
        ov += *(const f32x4*)(z + 3072 + n);
    }
    for (int i = 0; i < n2; ++i) {
        const float* z = pz2 + (size_t)i * 1048576 + (size_t)b * 4096;
        iv += *(const f32x4*)(z + n);
        fv += *(const f32x4*)(z + 1024 + n);
        gv += *(const f32x4*)(z + 2048 + n);
        ov += *(const f32x4*)(z + 3072 + n);
    }
    f32x4 cv = *(const f32x4*)(c_old + (size_t)b * 1024 + n);

    f32x4 hn, cn;
    ushort4_t hb;
#pragma unroll
    for (int j = 0; j < 4; ++j) {
        float ii = 1.f / (1.f + __expf(-iv[j]));
        float ff = 1.f / (1.f + __expf(-fv[j]));
        float gg = tanhf(gv[j]);
        float oo = 1.f / (1.f + __expf(-ov[j]));
        float c2 = ff * cv[j] + ii * gg;
        cn[j] = c2;
        float h2 = oo * tanhf(c2);
        hn[j] = h2;
        hb[j] = f2bf(h2);
    }
    *(f32x4*)(c_out + (size_t)b * 1024 + n) = cn;
    *(f32x4*)(h_out + (size_t)b * 1024 + n) = hn;
    *(ushort4_t*)(h_bf + (size_t)b * 1024 + n) = hb;
}

// ---------------------------------------------------------------------------
// logits = sum_kb zp[kb] + bp   (proj partial reduce), partial stride 131072
// ---------------------------------------------------------------------------
__global__ __launch_bounds__(256)
void finalize_proj(const float* __restrict__ zp, int nsplit,
                   const float* __restrict__ bp, float* __restrict__ logits)
{
    int t = blockIdx.x * 256 + threadIdx.x;   // 32768 threads x 4 elems
    int i = t * 4;
    f32x4 v = *(const f32x4*)(bp + (i & 511));
    for (int kb = 0; kb < nsplit; ++kb)
        v += *(const f32x4*)(zp + (size_t)kb * 131072 + i);
    *(f32x4*)(logits + i) = v;
}

// ---------------------------------------------------------------------------
// Pack fp32 -> bf16 for x, h0, h1, h2
// ---------------------------------------------------------------------------
__global__ __launch_bounds__(256)
void pack_bf16(const float* __restrict__ x,  const float* __restrict__ h0,
               const float* __restrict__ h1, const float* __restrict__ h2,
               unsigned short* __restrict__ xb,  unsigned short* __restrict__ h0b,
               unsigned short* __restrict__ h1b, unsigned short* __restrict__ h2b)
{
    int t = blockIdx.x * 256 + threadIdx.x;
    const float* src; unsigned short* dst; int off;
    if (t < 32768)       { src = x;  dst = xb;  off = t; }
    else if (t < 98304)  { src = h0; dst = h0b; off = t - 32768; }
    else if (t < 163840) { src = h1; dst = h1b; off = t - 98304; }
    else                 { src = h2; dst = h2b; off = t - 163840; }
    f32x4 v = *(const f32x4*)(src + (size_t)off * 4);
    ushort4_t o;
#pragma unroll
    for (int j = 0; j < 4; ++j) o[j] = f2bf(v[j]);
    *(ushort4_t*)(dst + (size_t)off * 4) = o;
}

// ---------------------------------------------------------------------------
extern "C" void kernel_launch(void* const* d_in, const int* in_sizes, int n_in,
                              void* d_out, int out_size, void* d_ws, size_t ws_size,
                              hipStream_t stream)
{
    const float* x  = (const float*)d_in[0];
    const float* h0 = (const float*)d_in[1];
    const float* c0 = (const float*)d_in[2];
    const float* h1 = (const float*)d_in[3];
    const float* c1 = (const float*)d_in[4];
    const float* h2 = (const float*)d_in[5];
    const float* c2 = (const float*)d_in[6];
    const float* W0 = (const float*)d_in[7];
    const float* U0 = (const float*)d_in[8];
    const float* b0 = (const float*)d_in[9];
    const float* W1 = (const float*)d_in[10];
    const float* U1 = (const float*)d_in[11];
    const float* b1 = (const float*)d_in[12];
    const float* W2 = (const float*)d_in[13];
    const float* U2 = (const float*)d_in[14];
    const float* b2 = (const float*)d_in[15];
    const float* Wp = (const float*)d_in[16];
    const float* bp = (const float*)d_in[17];

    float* out    = (float*)d_out;
    float* logits = out;                    // [256,512]
    float* h0n = out + 131072;              // [256,1024] each below
    float* c0n = h0n + 262144;
    float* h1n = c0n + 262144;
    float* c1n = h1n + 262144;
    float* h2n = c1n + 262144;
    float* c2n = h2n + 262144;

    const size_t SLOT = 1048576;            // floats per [256][4096] slot
    const size_t bf_bytes = 262144ull + 6ull * 524288ull;            // 3.25 MB
    const size_t need6 = 6ull * 4194304ull + bf_bytes;
    const size_t need4 = 4ull * 4194304ull + bf_bytes;
    const int nslots = (ws_size >= need6) ? 6 : (ws_size >= need4) ? 4 : 2;

    float* S = (float*)d_ws;
    auto S_at = [&](int i) { return S + (size_t)i * SLOT; };
    unsigned short* bufs = (unsigned short*)(S + (size_t)nslots * SLOT);
    unsigned short* xb   = bufs;
    unsigned short* h0b  = bufs + 131072;
    unsigned short* h1b  = h0b + 262144;
    unsigned short* h2b  = h1b + 262144;
    unsigned short* h0nb = h2b + 262144;
    unsigned short* h1nb = h0nb + 262144;
    unsigned short* h2nb = h1nb + 262144;

    pack_bf16<<<896, 256, 0, stream>>>(x, h0, h1, h2, xb, h0b, h1b, h2b);

    if (nslots == 6) {
        // mega: all 4 t=0-available products in one launch (56 MB of weights)
        GemmDesc mega;
        mega.p[0] = { xb,  W0, S_at(0), 512,  0, 0   };
        mega.p[1] = { h0b, U0, S_at(1), 1024, 0, 128 };
        mega.p[2] = { h1b, U1, S_at(4), 1024, 0, 256 };
        mega.p[3] = { h2b, U2, S_at(5), 1024, 0, 384 };
        mega.np = 4; mega.N = 4096;
        gemm_aw<<<512, 512, 0, stream>>>(mega);
        lstm_gates<<<256, 256, 0, stream>>>(S_at(0), 2, nullptr, 0, b0, c0,
                                            h0n, c0n, h0nb);

        GemmDesc g1;                        // K-split-4 -> 512 blocks, slots 0-3
        g1.p[0] = { h0nb, W1, S_at(0), 1024, 2, 0 };
        g1.p[1] = g1.p[2] = g1.p[3] = g1.p[0];
        g1.np = 1; g1.N = 4096;
        gemm_aw<<<512, 512, 0, stream>>>(g1);
        lstm_gates<<<256, 256, 0, stream>>>(S_at(0), 5, nullptr, 0, b1, c1,
                                            h1n, c1n, h1nb);   // slots0-3 + slot4(U1)

        GemmDesc g2;
        g2.p[0] = { h1nb, W2, S_at(0), 1024, 2, 0 };
        g2.p[1] = g2.p[2] = g2.p[3] = g2.p[0];
        g2.np = 1; g2.N = 4096;
        gemm_aw<<<512, 512, 0, stream>>>(g2);
        lstm_gates<<<256, 256, 0, stream>>>(S_at(0), 4, S_at(5), 1, b2, c2,
                                            h2n, c2n, h2nb);

        GemmDesc gp;                        // K-split-8 -> 128 blocks, slot 0
        gp.p[0] = { h2nb, Wp, S_at(0), 1024, 3, 0 };
        gp.p[1] = gp.p[2] = gp.p[3] = gp.p[0];
        gp.np = 1; gp.N = 512;
        gemm_aw<<<128, 512, 0, stream>>>(gp);
        finalize_proj<<<128, 256, 0, stream>>>(S_at(0), 8, bp, logits);
    } else {
        // sequential: merge each layer's W-product with the next U-product
        const int lgsM = (nslots >= 4) ? 1 : 0;
        const int nsp  = 1 << lgsM;

        GemmDesc m1;
        m1.p[0] = { xb,  W0, S_at(0),   512,  lgsM, 0         };
        m1.p[1] = { h0b, U0, S_at(nsp), 1024, lgsM, 128 * nsp };
        m1.p[2] = m1.p[3] = m1.p[1];
        m1.np = 2; m1.N = 4096;
        gemm_aw<<<256 * nsp, 512, 0, stream>>>(m1);
        lstm_gates<<<256, 256, 0, stream>>>(S_at(0), 2 * nsp, nullptr, 0, b0, c0,
                                            h0n, c0n, h0nb);
        GemmDesc m2;
        m2.p[0] = { h0nb, W1, S_at(0),   1024, lgsM, 0         };
        m2.p[1] = { h1b,  U1, S_at(nsp), 1024, lgsM, 128 * nsp };
        m2.p[2] = m2.p[3] = m2.p[1];
        m2.np = 2; m2.N = 4096;
        gemm_aw<<<256 * nsp, 512, 0, stream>>>(m2);
        lstm_gates<<<256, 256, 0, stream>>>(S_at(0), 2 * nsp, nullptr, 0, b1, c1,
                                            h1n, c1n, h1nb);
        GemmDesc m3;
        m3.p[0] = { h1nb, W2, S_at(0),   1024, lgsM, 0         };
        m3.p[1] = { h2b,  U2, S_at(nsp), 1024, lgsM, 128 * nsp };
        m3.p[2] = m3.p[3] = m3.p[1];
        m3.np = 2; m3.N = 4096;
        gemm_aw<<<256 * nsp, 512, 0, stream>>>(m3);
        lstm_gates<<<256, 256, 0, stream>>>(S_at(0), 2 * nsp, nullptr, 0, b2, c2,
                                            h2n, c2n, h2nb);

        GemmDesc gp;                        // K-split-8 -> 128 blocks, slot 0
        gp.p[0] = { h2nb, Wp, S_at(0), 1024, 3, 0 };
        gp.p[1] = gp.p[2] = gp.p[3] = gp.p[0];
        gp.np = 1; gp.N = 512;
        gemm_aw<<<128, 512, 0, stream>>>(gp);
        finalize_proj<<<128, 256, 0, stream>>>(S_at(0), 8, bp, logits);
    }
}

// Round 7
// 87.092 us; speedup vs baseline: 1.1664x; 1.1664x over previous
//
#include <hip/hip_runtime.h>

// ---------------------------------------------------------------------------
// Stacked 3-layer LSTM step + projection, B=256, I=512, H=1024, V=512 (fp32 io)
// Round 7: fragment-prepacked A.
//   A' layout: [kt32][mt][lane][8] bf16 -- one MFMA A-fragment = one coalesced
//   64-lane x 16B load (no LDS, no barrier, no scatter). pack/gates write it.
//   W: fp32 -> bf16 transpose via 2x4KB LDS dbuf, depth-4 register prefetch,
//   raw s_barrier + lgkmcnt(0) (vmcnt stays counted across barriers).
//   BM=256 (W read once) x BN=32, 512 thr, 2 blocks/CU.
// Launch graph: pack -> mega{x@W0,h0@U0,h1@U1,h2@U2} -> gates0 -> h0n@W1 ->
// gates1 -> h1n@W2 -> gates2 -> h2n@Wp -> finalize.
// ---------------------------------------------------------------------------

typedef __attribute__((ext_vector_type(8))) short short8_t;            // 8 bf16 (MFMA frag)
typedef __attribute__((ext_vector_type(8))) unsigned short ushort8_t;  // 16B st
typedef __attribute__((ext_vector_type(4))) float f32x4;               // MFMA acc / 16B ld

__device__ __forceinline__ unsigned short f2bf(float f) {
    union { float f; unsigned u; } v; v.f = f;
    unsigned r = v.u + 0x7FFFu + ((v.u >> 16) & 1u);   // RTNE (finite inputs)
    return (unsigned short)(r >> 16);
}

#define KT 64
#define BN 32

struct GemmPiece {
    const unsigned short* A;   // packed A' [K/32][16][64][8] bf16 bits
    const float*          W;   // [K][N] fp32
    float*                Z;   // partials: [1<<lgs][256][N]
    int K;
    int lgs;                   // K-split log2
    int bstart;                // first block id of this piece
};
struct GemmDesc { GemmPiece p[4]; int np; int N; };

// ---------------------------------------------------------------------------
// Z[kb][256][N] = A[256][K-slice kb] @ W[K-slice kb][N]   (per piece)
// 512 thr (8 waves), BM=256, BN=32. Wave w: rows w*32..+32 (m-subtiles 2w,
// 2w+1), 2x2 MFMA tiles. A frags: coalesced 16B loads from packed layout.
// ---------------------------------------------------------------------------
__global__ __launch_bounds__(512, 4)
void gemm_pk(GemmDesc d)
{
    __shared__ unsigned short Wl0[BN * KT];    // 4 KB, [n][k] transposed, swizzled
    __shared__ unsigned short Wl1[BN * KT];    // 4 KB

    const int bid = blockIdx.x;
    int pi = 0;
#pragma unroll
    for (int i = 1; i < 4; ++i)
        if (i < d.np && bid >= d.p[i].bstart) pi = i;
    const unsigned short* __restrict__ A = d.p[pi].A;
    const float* __restrict__ W = d.p[pi].W;
    const int K   = d.p[pi].K;
    const int lgs = d.p[pi].lgs;
    const int N   = d.N;
    const int lb  = bid - d.p[pi].bstart;
    const int nsplit = 1 << lgs;
    const int kb  = lb & (nsplit - 1);
    const int ns  = lb >> lgs;

    const int tid  = threadIdx.x;
    const int lane = tid & 63;
    const int w    = tid >> 6;
    const int lg   = lane >> 4;
    const int lr   = lane & 15;
    const int n0   = ns * BN;
    const int m0   = w * 32;
    const int klen = K >> lgs;
    const int kbeg = kb * klen;
    const int nt   = klen >> 6;            // >= 2 always
    const int ktb  = kbeg >> 5;            // base k-tile-of-32
    const int mt0  = w * 2;                // wave's first m-subtile

    const int wkr = tid >> 3;              // W k-row within tile 0..63
    const int wcq = tid & 7;               // W float4-col 0..7

    // register prefetch sets (statically named - rule #20)
    short8_t aA[4], aB[4];                 // A frags: (ks0,mt0),(ks0,mt0+1),(ks1,mt0),(ks1,mt0+1)
    f32x4    w0v, w1v, w2v, w3v;           // W row-chunks (depth 4)

    f32x4 acc00 = {0,0,0,0}, acc01 = {0,0,0,0}, acc10 = {0,0,0,0}, acc11 = {0,0,0,0};

    auto issueW = [&](int t, f32x4& wv) {
        wv = *(const f32x4*)(W + (size_t)(kbeg + t * KT + wkr) * N + n0 + wcq * 4);
    };

    auto issueA = [&](int t, short8_t (&a)[4]) {
        // frag(kt32, mt) at A' + ((kt32*16 + mt)*64 + lane)*8 ; 512 = 64*8
        const unsigned short* base = A + (((size_t)(ktb + t * 2) * 16 + mt0) * 64 + lane) * 8;
        a[0] = *(const short8_t*)(base);             // ks0, mt0
        a[1] = *(const short8_t*)(base + 512);       // ks0, mt0+1
        a[2] = *(const short8_t*)(base + 16 * 512);  // ks1, mt0
        a[3] = *(const short8_t*)(base + 17 * 512);  // ks1, mt0+1
    };

    auto stageW = [&](const f32x4& wv, unsigned short* wl) {
        int kch = wkr >> 3, kwi = wkr & 7;
#pragma unroll
        for (int j = 0; j < 4; ++j) {
            int n = wcq * 4 + j;           // transposed: Wl[n][k], 16B-chunk XOR swizzle
            wl[n * KT + ((kch ^ (n & 7)) << 3) + kwi] = f2bf(wv[j]);
        }
    };

    auto compute = [&](const unsigned short* wl, short8_t (&a)[4]) {
#pragma unroll
        for (int ks = 0; ks < 2; ++ks) {
            int ch = ks * 4 + lg;
            int nb0 = lr, nb1 = 16 + lr;
            short8_t b0f = *(const short8_t*)(wl + nb0 * KT + ((ch ^ (nb0 & 7)) << 3));
            short8_t b1f = *(const short8_t*)(wl + nb1 * KT + ((ch ^ (nb1 & 7)) << 3));
            acc00 = __builtin_amdgcn_mfma_f32_16x16x32_bf16(a[ks * 2],     b0f, acc00, 0, 0, 0);
            acc01 = __builtin_amdgcn_mfma_f32_16x16x32_bf16(a[ks * 2],     b1f, acc01, 0, 0, 0);
            acc10 = __builtin_amdgcn_mfma_f32_16x16x32_bf16(a[ks * 2 + 1], b0f, acc10, 0, 0, 0);
            acc11 = __builtin_amdgcn_mfma_f32_16x16x32_bf16(a[ks * 2 + 1], b1f, acc11, 0, 0, 0);
        }
    };

#define BAR() do { asm volatile("s_waitcnt lgkmcnt(0)" ::: "memory"); \
                   __builtin_amdgcn_s_barrier(); } while (0)

    // prologue: W depth-4, A depth-2, tile 0 staged
    issueW(0, w0v);
    if (1 < nt) issueW(1, w1v);
    if (2 < nt) issueW(2, w2v);
    if (3 < nt) issueW(3, w3v);
    issueA(0, aA);
    if (1 < nt) issueA(1, aB);
    stageW(w0v, Wl0);
    BAR();                                 // Wl0 (tile 0) published

    // phase p: stage w[(p+1)&3] -> Wl[(p+1)&1]; issueW(p+4) -> w[p&3];
    //          compute(Wl[p&1], a[p&1]); issueA(p+2) -> a[p&1]; barrier.
#define PHASE(p, WST, WLST, WIS, WLC, AC) \
    if ((p) < nt) { \
        if ((p) + 1 < nt) stageW(WST, WLST); \
        if ((p) + 4 < nt) issueW((p) + 4, WIS); \
        compute(WLC, AC); \
        if ((p) + 2 < nt) issueA((p) + 2, AC); \
        BAR(); \
    }

    for (int t = 0; t < nt; t += 4) {
        PHASE(t + 0, w1v, Wl1, w0v, Wl0, aA)
        PHASE(t + 1, w2v, Wl0, w1v, Wl1, aB)
        PHASE(t + 2, w3v, Wl1, w2v, Wl0, aA)
        PHASE(t + 3, w0v, Wl0, w3v, Wl1, aB)
    }
#undef PHASE
#undef BAR

    // epilogue: D mapping col=lane&15, row=4*(lane>>4)+reg  [m89/m91]
    float* zrow = d.p[pi].Z + (size_t)kb * 256 * N;
#pragma unroll
    for (int r = 0; r < 4; ++r) {
        int ma = m0 + lg * 4 + r;
        int mb = ma + 16;
        zrow[(size_t)ma * N + n0 + lr]      = acc00[r];
        zrow[(size_t)ma * N + n0 + 16 + lr] = acc01[r];
        zrow[(size_t)mb * N + n0 + lr]      = acc10[r];
        zrow[(size_t)mb * N + n0 + 16 + lr] = acc11[r];
    }
}

// ---------------------------------------------------------------------------
// Gates: z = sum(pz1[0..n1)) + sum(pz2[0..n2)) + bias -> h,c fp32 + h packed
// bf16 (fragment layout). Thread t -> (kt=t>>10, mt=(t>>6)&15, lane=t&63):
// b = mt*16+(lane&15), n0 = kt*32+(lane>>4)*8; handles 8 cols. 32768 threads.
// ---------------------------------------------------------------------------
__global__ __launch_bounds__(256)
void lstm_gates(const float* __restrict__ pz1, int n1,
                const float* __restrict__ pz2, int n2,
                const float* __restrict__ bias, const float* __restrict__ c_old,
                float* __restrict__ h_out, float* __restrict__ c_out,
                unsigned short* __restrict__ h_pk)
{
    int t = blockIdx.x * 256 + threadIdx.x;
    int lane = t & 63, mt = (t >> 6) & 15, kt = t >> 10;
    int b  = mt * 16 + (lane & 15);
    int n0 = kt * 32 + (lane >> 4) * 8;

    f32x4 ga[4], gb[4];
#pragma unroll
    for (int g = 0; g < 4; ++g) {
        ga[g] = *(const f32x4*)(bias + g * 1024 + n0);
        gb[g] = *(const f32x4*)(bias + g * 1024 + n0 + 4);
    }
    for (int i = 0; i < n1; ++i) {
        const float* z = pz1 + (size_t)i * 1048576 + (size_t)b * 4096;
#pragma unroll
        for (int g = 0; g < 4; ++g) {
            ga[g] += *(const f32x4*)(z + g * 1024 + n0);
            gb[g] += *(const f32x4*)(z + g * 1024 + n0 + 4);
        }
    }
    for (int i = 0; i < n2; ++i) {
        const float* z = pz2 + (size_t)i * 1048576 + (size_t)b * 4096;
#pragma unroll
        for (int g = 0; g < 4; ++g) {
            ga[g] += *(const f32x4*)(z + g * 1024 + n0);
            gb[g] += *(const f32x4*)(z + g * 1024 + n0 + 4);
        }
    }
    f32x4 ca = *(const f32x4*)(c_old + (size_t)b * 1024 + n0);
    f32x4 cb = *(const f32x4*)(c_old + (size_t)b * 1024 + n0 + 4);

    f32x4 hna, hnb, cna, cnb;
    ushort8_t hp;
#pragma unroll
    for (int j = 0; j < 4; ++j) {
        float ii = 1.f / (1.f + __expf(-ga[0][j]));
        float ff = 1.f / (1.f + __expf(-ga[1][j]));
        float gg = tanhf(ga[2][j]);
        float oo = 1.f / (1.f + __expf(-ga[3][j]));
        float c2 = ff * ca[j] + ii * gg;
        cna[j] = c2;
        float h2 = oo * tanhf(c2);
        hna[j] = h2;
        hp[j]  = f2bf(h2);
    }
#pragma unroll
    for (int j = 0; j < 4; ++j) {
        float ii = 1.f / (1.f + __expf(-gb[0][j]));
        float ff = 1.f / (1.f + __expf(-gb[1][j]));
        float gg = tanhf(gb[2][j]);
        float oo = 1.f / (1.f + __expf(-gb[3][j]));
        float c2 = ff * cb[j] + ii * gg;
        cnb[j] = c2;
        float h2 = oo * tanhf(c2);
        hnb[j] = h2;
        hp[4 + j] = f2bf(h2);
    }
    *(f32x4*)(c_out + (size_t)b * 1024 + n0)     = cna;
    *(f32x4*)(c_out + (size_t)b * 1024 + n0 + 4) = cnb;
    *(f32x4*)(h_out + (size_t)b * 1024 + n0)     = hna;
    *(f32x4*)(h_out + (size_t)b * 1024 + n0 + 4) = hnb;
    *(ushort8_t*)(h_pk + (size_t)t * 8) = hp;      // packed-fragment, coalesced
}

// ---------------------------------------------------------------------------
// logits = sum_kb zp[kb] + bp   (proj partial reduce), partial stride 131072
// ---------------------------------------------------------------------------
__global__ __launch_bounds__(256)
void finalize_proj(const float* __restrict__ zp, int nsplit,
                   const float* __restrict__ bp, float* __restrict__ logits)
{
    int t = blockIdx.x * 256 + threadIdx.x;   // 32768 threads x 4 elems
    int i = t * 4;
    f32x4 v = *(const f32x4*)(bp + (i & 511));
    for (int kb = 0; kb < nsplit; ++kb)
        v += *(const f32x4*)(zp + (size_t)kb * 131072 + i);
    *(f32x4*)(logits + i) = v;
}

// ---------------------------------------------------------------------------
// Pack fp32 -> packed-fragment bf16 for x, h0, h1, h2. 114688 threads.
// ---------------------------------------------------------------------------
__global__ __launch_bounds__(256)
void pack_pk(const float* __restrict__ x,  const float* __restrict__ h0,
             const float* __restrict__ h1, const float* __restrict__ h2,
             unsigned short* __restrict__ xb,  unsigned short* __restrict__ h0b,
             unsigned short* __restrict__ h1b, unsigned short* __restrict__ h2b)
{
    int t = blockIdx.x * 256 + threadIdx.x;
    const float* src; unsigned short* dst; int u, K;
    if (t < 16384)      { src = x;  dst = xb;  u = t;         K = 512;  }
    else if (t < 49152) { src = h0; dst = h0b; u = t - 16384; K = 1024; }
    else if (t < 81920) { src = h1; dst = h1b; u = t - 49152; K = 1024; }
    else                { src = h2; dst = h2b; u = t - 81920; K = 1024; }
    int lane = u & 63, mt = (u >> 6) & 15, kt = u >> 10;
    int b  = mt * 16 + (lane & 15);
    int n0 = kt * 32 + (lane >> 4) * 8;
    f32x4 v0 = *(const f32x4*)(src + (size_t)b * K + n0);
    f32x4 v1 = *(const f32x4*)(src + (size_t)b * K + n0 + 4);
    ushort8_t o;
#pragma unroll
    for (int j = 0; j < 4; ++j) { o[j] = f2bf(v0[j]); o[4 + j] = f2bf(v1[j]); }
    *(ushort8_t*)(dst + (size_t)u * 8) = o;
}

// ---------------------------------------------------------------------------
extern "C" void kernel_launch(void* const* d_in, const int* in_sizes, int n_in,
                              void* d_out, int out_size, void* d_ws, size_t ws_size,
                              hipStream_t stream)
{
    const float* x  = (const float*)d_in[0];
    const float* h0 = (const float*)d_in[1];
    const float* c0 = (const float*)d_in[2];
    const float* h1 = (const float*)d_in[3];
    const float* c1 = (const float*)d_in[4];
    const float* h2 = (const float*)d_in[5];
    const float* c2 = (const float*)d_in[6];
    const float* W0 = (const float*)d_in[7];
    const float* U0 = (const float*)d_in[8];
    const float* b0 = (const float*)d_in[9];
    const float* W1 = (const float*)d_in[10];
    const float* U1 = (const float*)d_in[11];
    const float* b1 = (const float*)d_in[12];
    const float* W2 = (const float*)d_in[13];
    const float* U2 = (const float*)d_in[14];
    const float* b2 = (const float*)d_in[15];
    const float* Wp = (const float*)d_in[16];
    const float* bp = (const float*)d_in[17];

    float* out    = (float*)d_out;
    float* logits = out;                    // [256,512]
    float* h0n = out + 131072;              // [256,1024] each below
    float* c0n = h0n + 262144;
    float* h1n = c0n + 262144;
    float* c1n = h1n + 262144;
    float* h2n = c1n + 262144;
    float* c2n = h2n + 262144;

    const size_t SLOT = 1048576;            // floats per [256][4096] slot
    const size_t bf_bytes = 262144ull + 6ull * 524288ull;            // 3.25 MB
    const size_t need6 = 6ull * 4194304ull + bf_bytes;
    const size_t need4 = 4ull * 4194304ull + bf_bytes;
    const int nslots = (ws_size >= need6) ? 6 : (ws_size >= need4) ? 4 : 2;

    float* S = (float*)d_ws;
    auto S_at = [&](int i) { return S + (size_t)i * SLOT; };
    unsigned short* bufs = (unsigned short*)(S + (size_t)nslots * SLOT);
    unsigned short* xb   = bufs;
    unsigned short* h0b  = bufs + 131072;
    unsigned short* h1b  = h0b + 262144;
    unsigned short* h2b  = h1b + 262144;
    unsigned short* h0nb = h2b + 262144;
    unsigned short* h1nb = h0nb + 262144;
    unsigned short* h2nb = h1nb + 262144;

    pack_pk<<<448, 256, 0, stream>>>(x, h0, h1, h2, xb, h0b, h1b, h2b);

    if (nslots == 6) {
        // mega: all 4 t=0-available products in one launch (56 MB of weights)
        GemmDesc mega;
        mega.p[0] = { xb,  W0, S_at(0), 512,  0, 0   };
        mega.p[1] = { h0b, U0, S_at(1), 1024, 0, 128 };
        mega.p[2] = { h1b, U1, S_at(4), 1024, 0, 256 };
        mega.p[3] = { h2b, U2, S_at(5), 1024, 0, 384 };
        mega.np = 4; mega.N = 4096;
        gemm_pk<<<512, 512, 0, stream>>>(mega);
        lstm_gates<<<128, 256, 0, stream>>>(S_at(0), 2, nullptr, 0, b0, c0,
                                            h0n, c0n, h0nb);

        GemmDesc g1;                        // K-split-4 -> 512 blocks, slots 0-3
        g1.p[0] = { h0nb, W1, S_at(0), 1024, 2, 0 };
        g1.p[1] = g1.p[2] = g1.p[3] = g1.p[0];
        g1.np = 1; g1.N = 4096;
        gemm_pk<<<512, 512, 0, stream>>>(g1);
        lstm_gates<<<128, 256, 0, stream>>>(S_at(0), 5, nullptr, 0, b1, c1,
                                            h1n, c1n, h1nb);   // slots 0-3 + slot4(U1)

        GemmDesc g2;
        g2.p[0] = { h1nb, W2, S_at(0), 1024, 2, 0 };
        g2.p[1] = g2.p[2] = g2.p[3] = g2.p[0];
        g2.np = 1; g2.N = 4096;
        gemm_pk<<<512, 512, 0, stream>>>(g2);
        lstm_gates<<<128, 256, 0, stream>>>(S_at(0), 4, S_at(5), 1, b2, c2,
                                            h2n, c2n, h2nb);

        GemmDesc gp;                        // K-split-8 -> 128 blocks, slot 0
        gp.p[0] = { h2nb, Wp, S_at(0), 1024, 3, 0 };
        gp.p[1] = gp.p[2] = gp.p[3] = gp.p[0];
        gp.np = 1; gp.N = 512;
        gemm_pk<<<128, 512, 0, stream>>>(gp);
        finalize_proj<<<128, 256, 0, stream>>>(S_at(0), 8, bp, logits);
    } else {
        // sequential: merge each layer's W-product with the next U-product
        const int lgsM = (nslots >= 4) ? 1 : 0;
        const int nsp  = 1 << lgsM;

        GemmDesc m1;
        m1.p[0] = { xb,  W0, S_at(0),   512,  lgsM, 0         };
        m1.p[1] = { h0b, U0, S_at(nsp), 1024, lgsM, 128 * nsp };
        m1.p[2] = m1.p[3] = m1.p[1];
        m1.np = 2; m1.N = 4096;
        gemm_pk<<<256 * nsp, 512, 0, stream>>>(m1);
        lstm_gates<<<128, 256, 0, stream>>>(S_at(0), 2 * nsp, nullptr, 0, b0, c0,
                                            h0n, c0n, h0nb);
        GemmDesc m2;
        m2.p[0] = { h0nb, W1, S_at(0),   1024, lgsM, 0         };
        m2.p[1] = { h1b,  U1, S_at(nsp), 1024, lgsM, 128 * nsp };
        m2.p[2] = m2.p[3] = m2.p[1];
        m2.np = 2; m2.N = 4096;
        gemm_pk<<<256 * nsp, 512, 0, stream>>>(m2);
        lstm_gates<<<128, 256, 0, stream>>>(S_at(0), 2 * nsp, nullptr, 0, b1, c1,
                                            h1n, c1n, h1nb);
        GemmDesc m3;
        m3.p[0] = { h1nb, W2, S_at(0),   1024, lgsM, 0         };
        m3.p[1] = { h2b,  U2, S_at(nsp), 1024, lgsM, 128 * nsp };
        m3.p[2] = m3.p[3] = m3.p[1];
        m3.np = 2; m3.N = 4096;
        gemm_pk<<<256 * nsp, 512, 0, stream>>>(m3);
        lstm_gates<<<128, 256, 0, stream>>>(S_at(0), 2 * nsp, nullptr, 0, b2, c2,
                                            h2n, c2n, h2nb);

        GemmDesc gp;                        // K-split-8 -> 128 blocks, slot 0
        gp.p[0] = { h2nb, Wp, S_at(0), 1024, 3, 0 };
        gp.p[1] = gp.p[2] = gp.p[3] = gp.p[0];
        gp.np = 1; gp.N = 512;
        gemm_pk<<<128, 512, 0, stream>>>(gp);
        finalize_proj<<<128, 256, 0, stream>>>(S_at(0), 8, bp, logits);
    }
}